// Round 15
// baseline (479.571 us; speedup 1.0000x reference)
//
#include <hip/hip_runtime.h>

// GMSA R15 = R14 (nontemporal streams) with compile fix: ext_vector types for
// nt builtins (u32x4/u32x2 instead of HIP uint4/uint2 at nt sites).
// d_out = [y (8,60,288,288), atn4, atn8, atn12] flat fp32.

constexpr int HW = 288 * 288;
constexpr long long ATN0_OFF = 39813120LL;
constexpr long long ATN1_OFF = ATN0_OFF + 41472LL * 256;
constexpr long long ATN2_OFF = ATN1_OFF + 10368LL * 4096;

// workspace layout: R5/R9/R10/R11/R13 EXACT
constexpr size_t YB_OFF = 0;                        // ybuf: 39,813,120 ushort
constexpr size_t WP_OFF = 79626240;                 // Wp: 7200 float
constexpr size_t BP_OFF = WP_OFF + 28800;           // bp: 128 float
constexpr size_t XP_OFF = BP_OFF + 512;             // xp: 39,813,120 ushort

typedef __attribute__((ext_vector_type(8))) short     bf16x8;
typedef __attribute__((ext_vector_type(4))) short     bf16x4;
typedef __attribute__((ext_vector_type(4))) float     f32x4;
typedef __attribute__((ext_vector_type(4))) unsigned  u32x4;
typedef __attribute__((ext_vector_type(2))) unsigned  u32x2;

__device__ __forceinline__ unsigned bfrnd(float f) {   // RNE to bf16 bits
    unsigned u = __float_as_uint(f);
    return (u + 0x7fffu + ((u >> 16) & 1u)) >> 16;
}
__device__ __forceinline__ unsigned bfpack(float a, float b) { return bfrnd(a) | (bfrnd(b) << 16); }

#if defined(__has_builtin)
#if __has_builtin(__builtin_amdgcn_mfma_f32_16x16x16bf16_1k)
#define HAVE_MFMA16 1
#endif
#endif

__device__ __forceinline__ f32x4 mfma16(bf16x4 a, bf16x4 b, f32x4 c) {
#ifdef HAVE_MFMA16
    return __builtin_amdgcn_mfma_f32_16x16x16bf16_1k(a, b, c, 0, 0, 0);
#else
    f32x4 d;
    asm("v_mfma_f32_16x16x16_bf16 %0, %1, %2, %3" : "=v"(d) : "v"(a), "v"(b), "v"(c));
    return d;
#endif
}

__device__ __forceinline__ f32x4 mfma32(bf16x8 a, bf16x8 b, f32x4 c) {
    return __builtin_amdgcn_mfma_f32_16x16x32_bf16(a, b, c, 0, 0, 0);
}

// ---------------- prep (R5 + bp zero-pad) ----------------
__global__ void prep_kernel(const float* __restrict__ W_in, const float* __restrict__ b_in,
                            const float* __restrict__ gamma, const float* __restrict__ beta,
                            const float* __restrict__ mean, const float* __restrict__ var,
                            float* __restrict__ Wp, float* __restrict__ bp) {
    int o = threadIdx.x;
    if (o < 120) {
        float inv = gamma[o] / sqrtf(var[o] + 1e-5f);
        for (int c = 0; c < 60; ++c) Wp[o * 60 + c] = W_in[o * 60 + c] * inv;
        bp[o] = b_in[o] * inv + beta[o] - mean[o] * inv;
    } else if (o < 128) {
        bp[o] = 0.f;
    }
}

// ---------------- proj_in (nt on x loads, xp stores) ----------------
__global__ __launch_bounds__(256, 3) void proj_in_kernel(const float* __restrict__ x,
                                                         const float* __restrict__ Wp,
                                                         const float* __restrict__ bp,
                                                         unsigned short* __restrict__ xp) {
    __shared__ __align__(16) unsigned short wq[128 * 64];
    __shared__ __align__(16) unsigned short ys[128 * 120];

    const int tid = threadIdx.x;
    const long long pixel0 = (long long)blockIdx.x * 128;
    const int b   = (int)(pixel0 / HW);
    const int hw0 = (int)(pixel0 % HW);

    for (int i = tid; i < 8192; i += 256) {
        const int row = i >> 6, ch = i & 63;
        wq[i] = (row < 120 && ch < 60) ? (unsigned short)bfrnd(Wp[row * 60 + ch]) : (unsigned short)0;
    }

    const int wave = tid >> 6, lane = tid & 63, lo = lane & 15, g = lane >> 4;

    u32x4 xlo[2], xhi[2];
    #pragma unroll
    for (int mt2 = 0; mt2 < 2; ++mt2) {
        const int row = (wave * 2 + mt2) * 16 + lo;
        const float* xb = x + (long long)b * 60 * HW + hw0 + row;
        unsigned short tl[8], th[8];
        #pragma unroll
        for (int e = 0; e < 8; ++e) {
            const int cl = g * 8 + e;
            tl[e] = (unsigned short)bfrnd(__builtin_nontemporal_load(&xb[(long long)cl * HW]));
            const int ch = 32 + g * 8 + e;
            th[e] = (ch < 60) ? (unsigned short)bfrnd(__builtin_nontemporal_load(&xb[(long long)ch * HW]))
                              : (unsigned short)0;
        }
        xlo[mt2] = *reinterpret_cast<const u32x4*>(tl);
        xhi[mt2] = *reinterpret_cast<const u32x4*>(th);
    }
    __syncthreads();

    #pragma unroll
    for (int n = 0; n < 8; ++n) {
        u32x4 wfl = *reinterpret_cast<const u32x4*>(&wq[(n * 16 + lo) * 64 + g * 8]);
        u32x4 wfh = *reinterpret_cast<const u32x4*>(&wq[(n * 16 + lo) * 64 + 32 + g * 8]);
        const int oc0 = n * 16 + 4 * g;
        const f32x4 bpv = *reinterpret_cast<const f32x4*>(&bp[oc0]);
        #pragma unroll
        for (int mt2 = 0; mt2 < 2; ++mt2) {
            f32x4 z = {0.f, 0.f, 0.f, 0.f};
            f32x4 acc = mfma32(*reinterpret_cast<bf16x8*>(&wfl),
                               *reinterpret_cast<bf16x8*>(&xlo[mt2]), z);
            acc = mfma32(*reinterpret_cast<bf16x8*>(&wfh),
                         *reinterpret_cast<bf16x8*>(&xhi[mt2]), acc);
            if (oc0 < 120) {
                const int pixel = (wave * 2 + mt2) * 16 + lo;
                u32x2 t;
                t.x = bfpack(acc[0] + bpv[0], acc[1] + bpv[1]);
                t.y = bfpack(acc[2] + bpv[2], acc[3] + bpv[3]);
                *reinterpret_cast<u32x2*>(&ys[pixel * 120 + oc0]) = t;
            }
        }
    }
    __syncthreads();

    for (int i = tid; i < 3 * 1280; i += 256) {
        const int br = i / 1280, j = i - br * 1280, p = j / 10, c = j - p * 10;
        const u32x2 v = *reinterpret_cast<const u32x2*>(&ys[p * 120 + br * 40 + c * 4]);
        __builtin_nontemporal_store(v,
            reinterpret_cast<u32x2*>(xp + ((long long)(b * 3 + br) * HW + hw0) * 40) + p * 10 + c);
    }
}

// ---------------- MFMA branch attention (nt on xp/atn/ybuf) ----------------
template <int WS, int NWIN, int BLOCK, int WPW, int BRANCH, int MINW>
__launch_bounds__(BLOCK, MINW)
__global__ void branch_kernel(const unsigned short* __restrict__ xp,
                              unsigned short* __restrict__ ybuf,
                              float* __restrict__ atn) {
    constexpr int P    = WS * WS;
    constexpr int RT   = P / 16;
    constexpr int SH   = WS / 2;
    constexpr int NWND = 288 / WS;
    constexpr int RSTR = 56;
    constexpr int WAVES = BLOCK / 64;
    constexpr int WINS_PER_WAVE = (NWIN * WPW) / WAVES;

    __shared__ __align__(16) unsigned short qv[NWIN * P * RSTR];
    __shared__ __align__(16) unsigned short ys[NWIN * P * 20];

    const int tid = threadIdx.x;
    const int w0 = blockIdx.x * NWIN;

    for (int idx = tid; idx < NWIN * P * 5; idx += BLOCK) {
        const int wl  = idx / (P * 5);
        const int rem = idx - wl * (P * 5);
        const int pix = rem / 5;
        const int ck  = rem - pix * 5;
        const int w   = w0 + wl;
        const int b   = w / (NWND * NWND);
        const int r2  = w - b * (NWND * NWND);
        const int wi  = r2 / NWND;
        const int wj  = r2 - wi * NWND;
        const int gh  = (wi * WS + pix / WS + SH) % 288;
        const int gw  = (wj * WS + pix % WS + SH) % 288;
        const u32x4 d = __builtin_nontemporal_load(reinterpret_cast<const u32x4*>(
            xp + ((long long)(b * 3 + BRANCH) * HW + gh * 288 + gw) * 40 + ck * 8));
        *reinterpret_cast<u32x4*>(&qv[(wl * P + pix) * RSTR + ck * 8]) = d;
    }
    __syncthreads();

    const int wave = tid >> 6;
    const int lane = tid & 63;
    const int lo   = lane & 15;
    const int g    = lane >> 4;

    for (int wk = 0; wk < WINS_PER_WAVE; ++wk) {
        const int wl   = (WPW == 1) ? (wave * WINS_PER_WAVE + wk) : (wave >> 1);
        const int half = (WPW == 1) ? 0 : (wave & 1);
        const int w    = w0 + wl;
        const unsigned short* wbase = qv + wl * P * RSTR;

        bf16x8 F[RT];
        #pragma unroll
        for (int t = 0; t < RT; ++t) {
            u32x4 u = *reinterpret_cast<const u32x4*>(&wbase[(16 * t + lo) * RSTR + g * 8]);
            if (g == 2) { u.z = 0; u.w = 0; }
            if (g == 3) { u.x = 0; u.y = 0; u.z = 0; u.w = 0; }
            F[t] = *reinterpret_cast<bf16x8*>(&u);
        }

        bf16x4 VB[RT][2];
        #pragma unroll
        for (int i = 0; i < RT; ++i) {
            #pragma unroll
            for (int ct = 0; ct < 2; ++ct) {
                const int c = ct * 16 + lo;
                bf16x4 vv;
                #pragma unroll
                for (int jj = 0; jj < 4; ++jj) {
                    const int row = 16 * i + 4 * g + jj;
                    vv[jj] = (c < 20) ? (short)wbase[row * RSTR + 20 + c] : (short)0;
                }
                VB[i][ct] = vv;
            }
        }

        const int jstart = (WPW == 1) ? 0 : (half * ((RT + 1) / 2));
        const int jend   = (WPW == 1) ? RT : ((half == 0) ? ((RT + 1) / 2) : RT);
        for (int j = jstart; j < jend; ++j) {
            f32x4 S[RT];
            #pragma unroll
            for (int i = 0; i < RT; ++i) {
                f32x4 z = {0.f, 0.f, 0.f, 0.f};
                S[i] = mfma32(F[i], F[j], z);
            }

            float m = S[0][0];
            #pragma unroll
            for (int i = 0; i < RT; ++i) {
                #pragma unroll
                for (int r = 0; r < 4; ++r) m = fmaxf(m, S[i][r]);
            }
            m = fmaxf(m, __shfl_xor(m, 16));
            m = fmaxf(m, __shfl_xor(m, 32));
            float sum = 0.f;
            #pragma unroll
            for (int i = 0; i < RT; ++i) {
                #pragma unroll
                for (int r = 0; r < 4; ++r) { float e = __expf(S[i][r] - m); S[i][r] = e; sum += e; }
            }
            sum += __shfl_xor(sum, 16);
            sum += __shfl_xor(sum, 32);
            const float inv = 1.0f / sum;
            #pragma unroll
            for (int i = 0; i < RT; ++i) {
                S[i][0] *= inv; S[i][1] *= inv; S[i][2] *= inv; S[i][3] *= inv;
            }

            float* arow = atn + ((long long)w * P + 16 * j + lo) * P + 4 * g;
            #pragma unroll
            for (int i = 0; i < RT; ++i)
                __builtin_nontemporal_store(S[i], reinterpret_cast<f32x4*>(arow + 16 * i));

            f32x4 Y0 = {0.f, 0.f, 0.f, 0.f};
            f32x4 Y1 = {0.f, 0.f, 0.f, 0.f};
            #pragma unroll
            for (int i = 0; i < RT; ++i) {
                u32x2 t2;
                t2.x = bfpack(S[i][0], S[i][1]);
                t2.y = bfpack(S[i][2], S[i][3]);
                bf16x4 pa = *reinterpret_cast<bf16x4*>(&t2);
                Y0 = mfma16(pa, VB[i][0], Y0);
                Y1 = mfma16(pa, VB[i][1], Y1);
            }

            unsigned short* ywp = ys + (wl * P + 16 * j + 4 * g) * 20;
            #pragma unroll
            for (int r = 0; r < 4; ++r) ywp[r * 20 + lo] = (unsigned short)bfrnd(Y0[r]);
            if (lo < 4) {
                #pragma unroll
                for (int r = 0; r < 4; ++r) ywp[r * 20 + 16 + lo] = (unsigned short)bfrnd(Y1[r]);
            }
        }
    }
    __syncthreads();

    for (int i = tid; i < NWIN * P * 5; i += BLOCK) {
        const int wl   = i / (P * 5);
        const int rem  = i - wl * (P * 5);
        const int pixr = rem / 5;
        const int c    = rem - pixr * 5;
        const int w2   = w0 + wl;
        const int b2   = w2 / (NWND * NWND);
        const int r2   = w2 - b2 * (NWND * NWND);
        const int wi2  = r2 / NWND;
        const int wj2  = r2 - wi2 * NWND;
        const int oh   = (wi2 * WS + pixr / WS + SH) % 288;
        const int ow   = (wj2 * WS + pixr % WS + SH) % 288;
        const u32x2 v = *reinterpret_cast<const u32x2*>(&ys[(wl * P + pixr) * 20 + c * 4]);
        __builtin_nontemporal_store(v, reinterpret_cast<u32x2*>(
            ybuf + ((long long)(b2 * 3 + BRANCH) * HW + oh * 288 + ow) * 20 + c * 4));
    }
}

// ---------------- proj_out (nt on ybuf loads, out stores) ----------------
__global__ __launch_bounds__(256, 4) void proj_out_kernel(const unsigned short* __restrict__ ybuf,
                                                          const float* __restrict__ W_out,
                                                          const float* __restrict__ bout,
                                                          float* __restrict__ out) {
    __shared__ __align__(16) unsigned short yh[128 * 72];
    __shared__ __align__(16) unsigned short wq[64 * 64];

    const int tid = threadIdx.x;
    const long long pixel0 = (long long)blockIdx.x * 128;
    const int b   = (int)(pixel0 / HW);
    const int hw0 = (int)(pixel0 % HW);

    for (int i = tid; i < 4096; i += 256) {
        const int row = i >> 6, ch = i & 63;
        wq[i] = (row < 60 && ch < 60) ? (unsigned short)bfrnd(W_out[row * 60 + ch]) : (unsigned short)0;
    }

    for (int i = tid; i < 1920; i += 256) {
        const int br = i / 640, j = i - br * 640, p = j / 5, c = j - p * 5;
        const u32x2 v = __builtin_nontemporal_load(reinterpret_cast<const u32x2*>(
            ybuf + ((long long)(b * 3 + br) * HW + hw0) * 20) + j);
        *reinterpret_cast<u32x2*>(&yh[p * 72 + br * 20 + c * 4]) = v;
    }
    {
        const int p = tid >> 1, hh = tid & 1;
        u32x2 zz; zz.x = 0; zz.y = 0;
        *reinterpret_cast<u32x2*>(&yh[p * 72 + 60 + hh * 4]) = zz;
    }
    __syncthreads();

    const int wave = tid >> 6, lane = tid & 63, lo = lane & 15, g = lane >> 4;

    u32x4 alo[2], ahi[2];
    #pragma unroll
    for (int mt2 = 0; mt2 < 2; ++mt2) {
        const int row = (wave * 2 + mt2) * 16 + lo;
        alo[mt2] = *reinterpret_cast<const u32x4*>(&yh[row * 72 + g * 8]);
        ahi[mt2] = *reinterpret_cast<const u32x4*>(&yh[row * 72 + 32 + g * 8]);
    }

    #pragma unroll
    for (int n = 0; n < 4; ++n) {
        u32x4 wfl = *reinterpret_cast<const u32x4*>(&wq[(n * 16 + lo) * 64 + g * 8]);
        u32x4 wfh = *reinterpret_cast<const u32x4*>(&wq[(n * 16 + lo) * 64 + 32 + g * 8]);
        const int oc = n * 16 + lo;
        const float bo = (oc < 60) ? bout[oc] : 0.f;
        #pragma unroll
        for (int mt2 = 0; mt2 < 2; ++mt2) {
            f32x4 z = {0.f, 0.f, 0.f, 0.f};
            f32x4 acc = mfma32(*reinterpret_cast<bf16x8*>(&alo[mt2]),
                               *reinterpret_cast<bf16x8*>(&wfl), z);
            acc = mfma32(*reinterpret_cast<bf16x8*>(&ahi[mt2]),
                         *reinterpret_cast<bf16x8*>(&wfh), acc);
            if (oc < 60) {
                const int px = (wave * 2 + mt2) * 16 + 4 * g;
                f32x4 v;
                v[0] = acc[0] + bo; v[1] = acc[1] + bo;
                v[2] = acc[2] + bo; v[3] = acc[3] + bo;
                __builtin_nontemporal_store(v, reinterpret_cast<f32x4*>(
                    &out[((long long)b * 60 + oc) * HW + hw0 + px]));
            }
        }
    }
}

extern "C" void kernel_launch(void* const* d_in, const int* in_sizes, int n_in,
                              void* d_out, int out_size, void* d_ws, size_t ws_size,
                              hipStream_t stream) {
    const float* x     = (const float*)d_in[0];
    const float* W_in  = (const float*)d_in[1];
    const float* b_in  = (const float*)d_in[2];
    const float* gamma = (const float*)d_in[3];
    const float* beta  = (const float*)d_in[4];
    const float* mean  = (const float*)d_in[5];
    const float* var   = (const float*)d_in[6];
    const float* Wout  = (const float*)d_in[7];
    const float* bout  = (const float*)d_in[8];
    float* out = (float*)d_out;

    char* wsb = (char*)d_ws;
    unsigned short* ybuf = (unsigned short*)(wsb + YB_OFF);
    float*          Wp   = (float*)(wsb + WP_OFF);
    float*          bp   = (float*)(wsb + BP_OFF);
    unsigned short* xp   = (unsigned short*)(wsb + XP_OFF);

    prep_kernel<<<1, 128, 0, stream>>>(W_in, b_in, gamma, beta, mean, var, Wp, bp);
    proj_in_kernel<<<5184, 256, 0, stream>>>(x, Wp, bp, xp);

    branch_kernel<4,  8, 128, 1, 0, 4><<<5184, 128, 0, stream>>>(xp, ybuf, out + ATN0_OFF);
    branch_kernel<8,  2, 128, 1, 1, 4><<<5184, 128, 0, stream>>>(xp, ybuf, out + ATN1_OFF);
    branch_kernel<12, 1, 128, 2, 2, 3><<<4608, 128, 0, stream>>>(xp, ybuf, out + ATN2_OFF);

    proj_out_kernel<<<5184, 256, 0, stream>>>(ybuf, Wout, bout, out);
}

// Round 16
// 439.163 us; speedup vs baseline: 1.0920x; 1.0920x over previous
//
#include <hip/hip_runtime.h>

// GMSA R16 = R13 + (1) nt ONLY on true output streams (atn, out) so xp/ybuf
// stay Infinity-Cache-resident across kernels; (2) tree-structured softmax
// max/sum (4 independent chains) to cut the serial fp dependency ~4x.
// d_out = [y (8,60,288,288), atn4, atn8, atn12] flat fp32.

constexpr int HW = 288 * 288;
constexpr long long ATN0_OFF = 39813120LL;
constexpr long long ATN1_OFF = ATN0_OFF + 41472LL * 256;
constexpr long long ATN2_OFF = ATN1_OFF + 10368LL * 4096;

// workspace layout: R5/R9/R10/R11/R13 EXACT
constexpr size_t YB_OFF = 0;                        // ybuf: 39,813,120 ushort
constexpr size_t WP_OFF = 79626240;                 // Wp: 7200 float
constexpr size_t BP_OFF = WP_OFF + 28800;           // bp: 128 float
constexpr size_t XP_OFF = BP_OFF + 512;             // xp: 39,813,120 ushort

typedef __attribute__((ext_vector_type(8))) short     bf16x8;
typedef __attribute__((ext_vector_type(4))) short     bf16x4;
typedef __attribute__((ext_vector_type(4))) float     f32x4;
typedef __attribute__((ext_vector_type(4))) unsigned  u32x4;
typedef __attribute__((ext_vector_type(2))) unsigned  u32x2;

__device__ __forceinline__ unsigned bfrnd(float f) {   // RNE to bf16 bits
    unsigned u = __float_as_uint(f);
    return (u + 0x7fffu + ((u >> 16) & 1u)) >> 16;
}
__device__ __forceinline__ unsigned bfpack(float a, float b) { return bfrnd(a) | (bfrnd(b) << 16); }

#if defined(__has_builtin)
#if __has_builtin(__builtin_amdgcn_mfma_f32_16x16x16bf16_1k)
#define HAVE_MFMA16 1
#endif
#endif

__device__ __forceinline__ f32x4 mfma16(bf16x4 a, bf16x4 b, f32x4 c) {
#ifdef HAVE_MFMA16
    return __builtin_amdgcn_mfma_f32_16x16x16bf16_1k(a, b, c, 0, 0, 0);
#else
    f32x4 d;
    asm("v_mfma_f32_16x16x16_bf16 %0, %1, %2, %3" : "=v"(d) : "v"(a), "v"(b), "v"(c));
    return d;
#endif
}

__device__ __forceinline__ f32x4 mfma32(bf16x8 a, bf16x8 b, f32x4 c) {
    return __builtin_amdgcn_mfma_f32_16x16x32_bf16(a, b, c, 0, 0, 0);
}

// ---------------- prep (R5 + bp zero-pad) ----------------
__global__ void prep_kernel(const float* __restrict__ W_in, const float* __restrict__ b_in,
                            const float* __restrict__ gamma, const float* __restrict__ beta,
                            const float* __restrict__ mean, const float* __restrict__ var,
                            float* __restrict__ Wp, float* __restrict__ bp) {
    int o = threadIdx.x;
    if (o < 120) {
        float inv = gamma[o] / sqrtf(var[o] + 1e-5f);
        for (int c = 0; c < 60; ++c) Wp[o * 60 + c] = W_in[o * 60 + c] * inv;
        bp[o] = b_in[o] * inv + beta[o] - mean[o] * inv;
    } else if (o < 128) {
        bp[o] = 0.f;
    }
}

// ---------------- proj_in (R13 verbatim: plain loads/stores) ----------------
__global__ __launch_bounds__(256, 3) void proj_in_kernel(const float* __restrict__ x,
                                                         const float* __restrict__ Wp,
                                                         const float* __restrict__ bp,
                                                         unsigned short* __restrict__ xp) {
    __shared__ __align__(16) unsigned short wq[128 * 64];
    __shared__ __align__(16) unsigned short ys[128 * 120];

    const int tid = threadIdx.x;
    const long long pixel0 = (long long)blockIdx.x * 128;
    const int b   = (int)(pixel0 / HW);
    const int hw0 = (int)(pixel0 % HW);

    for (int i = tid; i < 8192; i += 256) {
        const int row = i >> 6, ch = i & 63;
        wq[i] = (row < 120 && ch < 60) ? (unsigned short)bfrnd(Wp[row * 60 + ch]) : (unsigned short)0;
    }

    const int wave = tid >> 6, lane = tid & 63, lo = lane & 15, g = lane >> 4;

    u32x4 xlo[2], xhi[2];
    #pragma unroll
    for (int mt2 = 0; mt2 < 2; ++mt2) {
        const int row = (wave * 2 + mt2) * 16 + lo;
        const float* xb = x + (long long)b * 60 * HW + hw0 + row;
        unsigned short tl[8], th[8];
        #pragma unroll
        for (int e = 0; e < 8; ++e) {
            const int cl = g * 8 + e;
            tl[e] = (unsigned short)bfrnd(xb[(long long)cl * HW]);
            const int ch = 32 + g * 8 + e;
            th[e] = (ch < 60) ? (unsigned short)bfrnd(xb[(long long)ch * HW]) : (unsigned short)0;
        }
        xlo[mt2] = *reinterpret_cast<const u32x4*>(tl);
        xhi[mt2] = *reinterpret_cast<const u32x4*>(th);
    }
    __syncthreads();

    #pragma unroll
    for (int n = 0; n < 8; ++n) {
        u32x4 wfl = *reinterpret_cast<const u32x4*>(&wq[(n * 16 + lo) * 64 + g * 8]);
        u32x4 wfh = *reinterpret_cast<const u32x4*>(&wq[(n * 16 + lo) * 64 + 32 + g * 8]);
        const int oc0 = n * 16 + 4 * g;
        const f32x4 bpv = *reinterpret_cast<const f32x4*>(&bp[oc0]);
        #pragma unroll
        for (int mt2 = 0; mt2 < 2; ++mt2) {
            f32x4 z = {0.f, 0.f, 0.f, 0.f};
            f32x4 acc = mfma32(*reinterpret_cast<bf16x8*>(&wfl),
                               *reinterpret_cast<bf16x8*>(&xlo[mt2]), z);
            acc = mfma32(*reinterpret_cast<bf16x8*>(&wfh),
                         *reinterpret_cast<bf16x8*>(&xhi[mt2]), acc);
            if (oc0 < 120) {
                const int pixel = (wave * 2 + mt2) * 16 + lo;
                u32x2 t;
                t.x = bfpack(acc[0] + bpv[0], acc[1] + bpv[1]);
                t.y = bfpack(acc[2] + bpv[2], acc[3] + bpv[3]);
                *reinterpret_cast<u32x2*>(&ys[pixel * 120 + oc0]) = t;
            }
        }
    }
    __syncthreads();

    for (int i = tid; i < 3 * 1280; i += 256) {
        const int br = i / 1280, j = i - br * 1280, p = j / 10, c = j - p * 10;
        const u32x2 v = *reinterpret_cast<const u32x2*>(&ys[p * 120 + br * 40 + c * 4]);
        reinterpret_cast<u32x2*>(xp + ((long long)(b * 3 + br) * HW + hw0) * 40)[p * 10 + c] = v;
    }
}

// ---------------- MFMA branch attention (nt ONLY on atn; tree softmax) ----------------
template <int WS, int NWIN, int BLOCK, int WPW, int BRANCH, int MINW>
__launch_bounds__(BLOCK, MINW)
__global__ void branch_kernel(const unsigned short* __restrict__ xp,
                              unsigned short* __restrict__ ybuf,
                              float* __restrict__ atn) {
    constexpr int P    = WS * WS;
    constexpr int RT   = P / 16;
    constexpr int SH   = WS / 2;
    constexpr int NWND = 288 / WS;
    constexpr int RSTR = 56;
    constexpr int WAVES = BLOCK / 64;
    constexpr int WINS_PER_WAVE = (NWIN * WPW) / WAVES;

    __shared__ __align__(16) unsigned short qv[NWIN * P * RSTR];
    __shared__ __align__(16) unsigned short ys[NWIN * P * 20];

    const int tid = threadIdx.x;
    const int w0 = blockIdx.x * NWIN;

    for (int idx = tid; idx < NWIN * P * 5; idx += BLOCK) {
        const int wl  = idx / (P * 5);
        const int rem = idx - wl * (P * 5);
        const int pix = rem / 5;
        const int ck  = rem - pix * 5;
        const int w   = w0 + wl;
        const int b   = w / (NWND * NWND);
        const int r2  = w - b * (NWND * NWND);
        const int wi  = r2 / NWND;
        const int wj  = r2 - wi * NWND;
        const int gh  = (wi * WS + pix / WS + SH) % 288;
        const int gw  = (wj * WS + pix % WS + SH) % 288;
        const u32x4 d = *reinterpret_cast<const u32x4*>(
            xp + ((long long)(b * 3 + BRANCH) * HW + gh * 288 + gw) * 40 + ck * 8);
        *reinterpret_cast<u32x4*>(&qv[(wl * P + pix) * RSTR + ck * 8]) = d;
    }
    __syncthreads();

    const int wave = tid >> 6;
    const int lane = tid & 63;
    const int lo   = lane & 15;
    const int g    = lane >> 4;

    for (int wk = 0; wk < WINS_PER_WAVE; ++wk) {
        const int wl   = (WPW == 1) ? (wave * WINS_PER_WAVE + wk) : (wave >> 1);
        const int half = (WPW == 1) ? 0 : (wave & 1);
        const int w    = w0 + wl;
        const unsigned short* wbase = qv + wl * P * RSTR;

        bf16x8 F[RT];
        #pragma unroll
        for (int t = 0; t < RT; ++t) {
            u32x4 u = *reinterpret_cast<const u32x4*>(&wbase[(16 * t + lo) * RSTR + g * 8]);
            if (g == 2) { u.z = 0; u.w = 0; }
            if (g == 3) { u.x = 0; u.y = 0; u.z = 0; u.w = 0; }
            F[t] = *reinterpret_cast<bf16x8*>(&u);
        }

        bf16x4 VB[RT][2];
        #pragma unroll
        for (int i = 0; i < RT; ++i) {
            #pragma unroll
            for (int ct = 0; ct < 2; ++ct) {
                const int c = ct * 16 + lo;
                bf16x4 vv;
                #pragma unroll
                for (int jj = 0; jj < 4; ++jj) {
                    const int row = 16 * i + 4 * g + jj;
                    vv[jj] = (c < 20) ? (short)wbase[row * RSTR + 20 + c] : (short)0;
                }
                VB[i][ct] = vv;
            }
        }

        const int jstart = (WPW == 1) ? 0 : (half * ((RT + 1) / 2));
        const int jend   = (WPW == 1) ? RT : ((half == 0) ? ((RT + 1) / 2) : RT);
        for (int j = jstart; j < jend; ++j) {
            f32x4 S[RT];
            #pragma unroll
            for (int i = 0; i < RT; ++i) {
                f32x4 z = {0.f, 0.f, 0.f, 0.f};
                S[i] = mfma32(F[i], F[j], z);
            }

            // tree max: 4 independent per-register chains, then combine
            float m0 = S[0][0], m1 = S[0][1], m2 = S[0][2], m3 = S[0][3];
            #pragma unroll
            for (int i = 1; i < RT; ++i) {
                m0 = fmaxf(m0, S[i][0]); m1 = fmaxf(m1, S[i][1]);
                m2 = fmaxf(m2, S[i][2]); m3 = fmaxf(m3, S[i][3]);
            }
            float m = fmaxf(fmaxf(m0, m1), fmaxf(m2, m3));
            m = fmaxf(m, __shfl_xor(m, 16));
            m = fmaxf(m, __shfl_xor(m, 32));

            // exp + tree sum (4 independent accumulators)
            float s0 = 0.f, s1 = 0.f, s2 = 0.f, s3 = 0.f;
            #pragma unroll
            for (int i = 0; i < RT; ++i) {
                float e0 = __expf(S[i][0] - m); S[i][0] = e0; s0 += e0;
                float e1 = __expf(S[i][1] - m); S[i][1] = e1; s1 += e1;
                float e2 = __expf(S[i][2] - m); S[i][2] = e2; s2 += e2;
                float e3 = __expf(S[i][3] - m); S[i][3] = e3; s3 += e3;
            }
            float sum = (s0 + s1) + (s2 + s3);
            sum += __shfl_xor(sum, 16);
            sum += __shfl_xor(sum, 32);
            const float inv = 1.0f / sum;
            #pragma unroll
            for (int i = 0; i < RT; ++i) {
                S[i][0] *= inv; S[i][1] *= inv; S[i][2] *= inv; S[i][3] *= inv;
            }

            float* arow = atn + ((long long)w * P + 16 * j + lo) * P + 4 * g;
            #pragma unroll
            for (int i = 0; i < RT; ++i)
                __builtin_nontemporal_store(S[i], reinterpret_cast<f32x4*>(arow + 16 * i));

            f32x4 Y0 = {0.f, 0.f, 0.f, 0.f};
            f32x4 Y1 = {0.f, 0.f, 0.f, 0.f};
            #pragma unroll
            for (int i = 0; i < RT; ++i) {
                u32x2 t2;
                t2.x = bfpack(S[i][0], S[i][1]);
                t2.y = bfpack(S[i][2], S[i][3]);
                bf16x4 pa = *reinterpret_cast<bf16x4*>(&t2);
                Y0 = mfma16(pa, VB[i][0], Y0);
                Y1 = mfma16(pa, VB[i][1], Y1);
            }

            unsigned short* ywp = ys + (wl * P + 16 * j + 4 * g) * 20;
            #pragma unroll
            for (int r = 0; r < 4; ++r) ywp[r * 20 + lo] = (unsigned short)bfrnd(Y0[r]);
            if (lo < 4) {
                #pragma unroll
                for (int r = 0; r < 4; ++r) ywp[r * 20 + 16 + lo] = (unsigned short)bfrnd(Y1[r]);
            }
        }
    }
    __syncthreads();

    for (int i = tid; i < NWIN * P * 5; i += BLOCK) {
        const int wl   = i / (P * 5);
        const int rem  = i - wl * (P * 5);
        const int pixr = rem / 5;
        const int c    = rem - pixr * 5;
        const int w2   = w0 + wl;
        const int b2   = w2 / (NWND * NWND);
        const int r2   = w2 - b2 * (NWND * NWND);
        const int wi2  = r2 / NWND;
        const int wj2  = r2 - wi2 * NWND;
        const int oh   = (wi2 * WS + pixr / WS + SH) % 288;
        const int ow   = (wj2 * WS + pixr % WS + SH) % 288;
        const u32x2 v = *reinterpret_cast<const u32x2*>(&ys[(wl * P + pixr) * 20 + c * 4]);
        *reinterpret_cast<u32x2*>(
            ybuf + ((long long)(b2 * 3 + BRANCH) * HW + oh * 288 + ow) * 20 + c * 4) = v;
    }
}

// ---------------- proj_out (plain ybuf loads; nt out stores) ----------------
__global__ __launch_bounds__(256, 4) void proj_out_kernel(const unsigned short* __restrict__ ybuf,
                                                          const float* __restrict__ W_out,
                                                          const float* __restrict__ bout,
                                                          float* __restrict__ out) {
    __shared__ __align__(16) unsigned short yh[128 * 72];
    __shared__ __align__(16) unsigned short wq[64 * 64];

    const int tid = threadIdx.x;
    const long long pixel0 = (long long)blockIdx.x * 128;
    const int b   = (int)(pixel0 / HW);
    const int hw0 = (int)(pixel0 % HW);

    for (int i = tid; i < 4096; i += 256) {
        const int row = i >> 6, ch = i & 63;
        wq[i] = (row < 60 && ch < 60) ? (unsigned short)bfrnd(W_out[row * 60 + ch]) : (unsigned short)0;
    }

    for (int i = tid; i < 1920; i += 256) {
        const int br = i / 640, j = i - br * 640, p = j / 5, c = j - p * 5;
        const u32x2 v = reinterpret_cast<const u32x2*>(
            ybuf + ((long long)(b * 3 + br) * HW + hw0) * 20)[j];
        *reinterpret_cast<u32x2*>(&yh[p * 72 + br * 20 + c * 4]) = v;
    }
    {
        const int p = tid >> 1, hh = tid & 1;
        u32x2 zz; zz.x = 0; zz.y = 0;
        *reinterpret_cast<u32x2*>(&yh[p * 72 + 60 + hh * 4]) = zz;
    }
    __syncthreads();

    const int wave = tid >> 6, lane = tid & 63, lo = lane & 15, g = lane >> 4;

    u32x4 alo[2], ahi[2];
    #pragma unroll
    for (int mt2 = 0; mt2 < 2; ++mt2) {
        const int row = (wave * 2 + mt2) * 16 + lo;
        alo[mt2] = *reinterpret_cast<const u32x4*>(&yh[row * 72 + g * 8]);
        ahi[mt2] = *reinterpret_cast<const u32x4*>(&yh[row * 72 + 32 + g * 8]);
    }

    #pragma unroll
    for (int n = 0; n < 4; ++n) {
        u32x4 wfl = *reinterpret_cast<const u32x4*>(&wq[(n * 16 + lo) * 64 + g * 8]);
        u32x4 wfh = *reinterpret_cast<const u32x4*>(&wq[(n * 16 + lo) * 64 + 32 + g * 8]);
        const int oc = n * 16 + lo;
        const float bo = (oc < 60) ? bout[oc] : 0.f;
        #pragma unroll
        for (int mt2 = 0; mt2 < 2; ++mt2) {
            f32x4 z = {0.f, 0.f, 0.f, 0.f};
            f32x4 acc = mfma32(*reinterpret_cast<bf16x8*>(&alo[mt2]),
                               *reinterpret_cast<bf16x8*>(&wfl), z);
            acc = mfma32(*reinterpret_cast<bf16x8*>(&ahi[mt2]),
                         *reinterpret_cast<bf16x8*>(&wfh), acc);
            if (oc < 60) {
                const int px = (wave * 2 + mt2) * 16 + 4 * g;
                f32x4 v;
                v[0] = acc[0] + bo; v[1] = acc[1] + bo;
                v[2] = acc[2] + bo; v[3] = acc[3] + bo;
                __builtin_nontemporal_store(v, reinterpret_cast<f32x4*>(
                    &out[((long long)b * 60 + oc) * HW + hw0 + px]));
            }
        }
    }
}

extern "C" void kernel_launch(void* const* d_in, const int* in_sizes, int n_in,
                              void* d_out, int out_size, void* d_ws, size_t ws_size,
                              hipStream_t stream) {
    const float* x     = (const float*)d_in[0];
    const float* W_in  = (const float*)d_in[1];
    const float* b_in  = (const float*)d_in[2];
    const float* gamma = (const float*)d_in[3];
    const float* beta  = (const float*)d_in[4];
    const float* mean  = (const float*)d_in[5];
    const float* var   = (const float*)d_in[6];
    const float* Wout  = (const float*)d_in[7];
    const float* bout  = (const float*)d_in[8];
    float* out = (float*)d_out;

    char* wsb = (char*)d_ws;
    unsigned short* ybuf = (unsigned short*)(wsb + YB_OFF);
    float*          Wp   = (float*)(wsb + WP_OFF);
    float*          bp   = (float*)(wsb + BP_OFF);
    unsigned short* xp   = (unsigned short*)(wsb + XP_OFF);

    prep_kernel<<<1, 128, 0, stream>>>(W_in, b_in, gamma, beta, mean, var, Wp, bp);
    proj_in_kernel<<<5184, 256, 0, stream>>>(x, Wp, bp, xp);

    branch_kernel<4,  8, 128, 1, 0, 4><<<5184, 128, 0, stream>>>(xp, ybuf, out + ATN0_OFF);
    branch_kernel<8,  2, 128, 1, 1, 4><<<5184, 128, 0, stream>>>(xp, ybuf, out + ATN1_OFF);
    branch_kernel<12, 1, 128, 2, 2, 3><<<4608, 128, 0, stream>>>(xp, ybuf, out + ATN2_OFF);

    proj_out_kernel<<<5184, 256, 0, stream>>>(ybuf, Wout, bout, out);
}